// Round 16
// baseline (133.985 us; speedup 1.0000x reference)
//
#include <hip/hip_runtime.h>
#include <hip/hip_fp16.h>
#include <math.h>
#include <float.h>

#define DD   128
#define KX   65          // D/2+1
#define NB   4
#define NTT  2
#define NG   125
#define NBTG (NB*NTT*NG) // 1000
#define WIN  24
#define H0   52

// fp16 y-pair-packed padded volume: cell (z,y,x) = 8B, 4 halves:
// (re V[z][y][x], im V[z][y][x], re V[z][y+1][x], im V[z][y+1][x])
// z in [0,131], y in [0,130], x in [0,67]; V-interior at z,y in [1,128]
#define QZ  132
#define QY  131
#define QX  68
#define QPLANE (QY*QX)      // 8908
#define QN  (QZ*QY*QX)      // 1,175,856 cells (8B each)

typedef unsigned int u32;

__device__ __forceinline__ float2 cmul(float2 a, float2 b){
    return make_float2(a.x*b.x - a.y*b.y, a.x*b.y + a.y*b.x);
}

// inline twiddle table: sTw[m] = e^{+2*pi*i*m/128}
__device__ __forceinline__ void make_tw(float2* sTw, int tid){
    if (tid < 128){
        float s, c;
        sincosf((float)tid * (float)(M_PI/64.0), &s, &c);
        sTw[tid] = make_float2(c, s);
    }
}

// Stage A (fused): bid<512 -> vol rfft-x via 2-real-rows-as-complex +
// radix-4 x2 levels + 8-term dots + Hermitian unpack (sinc^2 via LDS table);
// 512<=bid<642 -> image rfft-x; bid>=642 -> zero the packed fp16 volume + cnt.
__global__ __launch_bounds__(256) void k_stageA(const float* __restrict__ vol,
                       const float* __restrict__ imgs,
                       float2* __restrict__ A1, float2* __restrict__ B1,
                       uint4* __restrict__ Yz, int n4, int* __restrict__ cnt){
    __shared__ float2 sZ [16*DD];   // 16 KB
    __shared__ float2 sZ2[16*DD];   // 16 KB
    __shared__ float2 sTw[128];
    __shared__ float  sSinc[257];
    int tid = threadIdx.x;
    int bid = blockIdx.x;

    if (bid >= 642){
        if (bid == 642 && tid == 0) *cnt = 0;
        int i = (bid - 642)*256 + tid;
        for (; i < n4; i += 256*256)
            Yz[i] = make_uint4(0,0,0,0);
        return;
    }
    make_tw(sTw, tid);

    if (bid < 512){
        // sinc^2 table over t = r^2 in [0, 0.75]
        for (int i = tid; i < 257; i += 256){
            float t = (float)i * (0.75f/256.f);
            float r = sqrtf(t);
            float s = (r > 0.f) ? (sinf((float)M_PI*r)/((float)M_PI*r)) : 1.f;
            sSinc[i] = s*s;
        }
        __syncthreads();
        int z = bid >> 2, q = bid & 3;
        int y0 = q*32;
        float fz = (z-64)*(1.0f/128.0f);
        float fz2 = fz*fz;
        for (int i = tid; i < 16*DD; i += 256){
            int p = i >> 7, x = i & 127;
            int yA = y0 + 2*p;
            float fx = (x-64)*(1.0f/128.0f);
            float fyA = (yA-64)*(1.0f/128.0f);
            float fyB = fyA + (1.0f/128.0f);
            float b2 = fz2 + fx*fx;
            float tA = (b2 + fyA*fyA) * (256.f/0.75f);
            float tB = (b2 + fyB*fyB) * (256.f/0.75f);
            int iA = min((int)tA, 255), iB = min((int)tB, 255);
            float frA = tA - (float)iA, frB = tB - (float)iB;
            float wA = sSinc[iA] + frA*(sSinc[iA+1]-sSinc[iA]);
            float wB = sSinc[iB] + frB*(sSinc[iB+1]-sSinc[iB]);
            float a = vol[(z*DD + yA)*DD + x] * wA;
            float b = vol[(z*DD + yA+1)*DD + x] * wB;
            sZ[i] = make_float2(a, b);
        }
        __syncthreads();
        // level 1 (forward)
        for (int i = tid; i < 16*32; i += 256){
            int p = i >> 5, x1 = i & 31;
            int b0 = p*DD + x1;
            float2 a = sZ[b0], bb = sZ[b0+32], c2 = sZ[b0+64], d = sZ[b0+96];
            float acx=a.x+c2.x, acy=a.y+c2.y;
            float amx=a.x-c2.x, amy=a.y-c2.y;
            float bdx=bb.x+d.x, bdy=bb.y+d.y;
            float bmx=bb.x-d.x, bmy=bb.y-d.y;
            sZ[b0   ] = make_float2(acx+bdx, acy+bdy);     // c=0
            sZ[b0+32] = make_float2(amx+bmy, amy-bmx);     // c=1: (a-c2)-i(b-d)
            sZ[b0+64] = make_float2(acx-bdx, acy-bdy);     // c=2
            sZ[b0+96] = make_float2(amx-bmy, amy+bmx);     // c=3: +i(b-d)
        }
        __syncthreads();
        // level 2 (forward, in place)
        for (int i = tid; i < 16*32; i += 256){
            int p = i >> 5, r5 = i & 31;
            int c = r5 >> 3, x2 = r5 & 7;
            int b0 = p*DD + 32*c + x2;
            float2 u0 = sZ[b0], u1 = sZ[b0+8], u2 = sZ[b0+16], u3 = sZ[b0+24];
            float2 w1 = sTw[(8*c)&127];  w1.y = -w1.y;
            float2 w2 = sTw[(16*c)&127]; w2.y = -w2.y;
            float2 w3 = sTw[(24*c)&127]; w3.y = -w3.y;
            float2 t1 = cmul(u1,w1), t2 = cmul(u2,w2), t3 = cmul(u3,w3);
            float2 pp = make_float2(u0.x+t2.x, u0.y+t2.y);
            float2 qq = make_float2(u0.x-t2.x, u0.y-t2.y);
            float2 rr = make_float2(t1.x+t3.x, t1.y+t3.y);
            float2 ss = make_float2(t1.x-t3.x, t1.y-t3.y);
            sZ[b0   ] = make_float2(pp.x+rr.x, pp.y+rr.y);   // s=0
            sZ[b0+8 ] = make_float2(qq.x+ss.y, qq.y-ss.x);   // s=1: q - i s
            sZ[b0+16] = make_float2(pp.x-rr.x, pp.y-rr.y);   // s=2
            sZ[b0+24] = make_float2(qq.x-ss.y, qq.y+ss.x);   // s=3: q + i s
        }
        __syncthreads();
        // 8-term dots
        for (int i = tid; i < 16*DD; i += 256){
            int p = i >> 7, k = i & 127;
            int c = k & 3, s = (k >> 2) & 3;
            const float2* v = &sZ[p*DD + 32*c + 8*s];
            float ar0=0,ai0=0,ar1=0,ai1=0;
            int j = 0;
            #pragma unroll
            for (int x2 = 0; x2 < 8; x2 += 2){
                float2 v0 = v[x2], v1 = v[x2+1];
                float2 e0 = sTw[j]; int jn = (j + k)&127;
                float2 e1 = sTw[jn];
                ar0 += v0.x*e0.x + v0.y*e0.y;  ai0 += v0.y*e0.x - v0.x*e0.y;
                ar1 += v1.x*e1.x + v1.y*e1.y;  ai1 += v1.y*e1.x - v1.x*e1.y;
                j = (jn + k)&127;
            }
            sZ2[i] = make_float2(ar0+ar1, ai0+ai1);
        }
        __syncthreads();
        // Hermitian unpack
        for (int i = tid; i < 16*KX; i += 256){
            int p = i / KX, k = i - p*KX;
            float2 Zk = sZ2[p*DD + k];
            float2 Zm = sZ2[p*DD + ((128-k)&127)];
            float2 A = make_float2(0.5f*(Zk.x+Zm.x), 0.5f*(Zk.y-Zm.y));
            float Dx = Zk.x - Zm.x, Dy = Zk.y + Zm.y;
            float2 Bv = make_float2(0.5f*Dy, -0.5f*Dx);
            int yA = y0 + 2*p;
            A1[(z*DD + yA  )*KX + k] = A;
            A1[(z*DD + yA+1)*KX + k] = Bv;
        }
    } else {
        __syncthreads();
        int o = (bid - 512)*256 + tid;
        if (o >= NB*DD*KX) return;
        int b = o / (DD*KX);
        int r = o - b*DD*KX;
        int y = r / KX, k = r - y*KX;
        const float* row = imgs + (b*DD + y)*DD;
        float ar0=0,ai0=0,ar1=0,ai1=0,ar2=0,ai2=0,ar3=0,ai3=0;
        int i0=0, i1=k&127, i2=(2*k)&127, i3=(3*k)&127;
        int st = (4*k)&127;
        for (int x = 0; x < DD; x += 4){
            float v0=row[x], v1=row[x+1], v2=row[x+2], v3=row[x+3];
            float2 e0=sTw[i0], e1=sTw[i1], e2=sTw[i2], e3=sTw[i3];
            ar0 += v0*e0.x; ai0 -= v0*e0.y;
            ar1 += v1*e1.x; ai1 -= v1*e1.y;
            ar2 += v2*e2.x; ai2 -= v2*e2.y;
            ar3 += v3*e3.x; ai3 -= v3*e3.y;
            i0=(i0+st)&127; i1=(i1+st)&127; i2=(i2+st)&127; i3=(i3+st)&127;
        }
        B1[o] = make_float2(ar0+ar1+ar2+ar3, ai0+ai1+ai2+ai3);
    }
}

// Stage B (fused): bid<512 -> vol fft-y radix-4 x2 levels (class per block);
//                  bid>=512 -> image fft-y + signs + ctf premul -> Fc.
__global__ __launch_bounds__(256) void k_stageB(const float2* __restrict__ A1,
                       const float* __restrict__ ctf, const float2* __restrict__ B1,
                       float2* __restrict__ A2, float2* __restrict__ Fc){
    __shared__ float2 sU[32*KX];   // 16640 B
    __shared__ float2 sTw[128];
    int tid = threadIdx.x;
    int bid = blockIdx.x;
    make_tw(sTw, tid);
    __syncthreads();

    if (bid < 512){
        int z = bid >> 2, c = bid & 3;
        const float2* base = A1 + z*DD*KX;
        for (int i = tid; i < 32*KX; i += 256){
            int n = i / KX, kk = i - n*KX;
            float2 a  = base[(n    )*KX + kk];
            float2 bb = base[(n+32)*KX + kk];
            float2 c2 = base[(n+64)*KX + kk];
            float2 d  = base[(n+96)*KX + kk];
            float acx = a.x + c2.x, acy = a.y + c2.y;
            float amx = a.x - c2.x, amy = a.y - c2.y;
            float bdx = bb.x + d.x, bdy = bb.y + d.y;
            float bmx = bb.x - d.x, bmy = bb.y - d.y;
            float2 u;
            if (c == 0)      u = make_float2(acx + bdx, acy + bdy);
            else if (c == 2) u = make_float2(acx - bdx, acy - bdy);
            else if (c == 1) u = make_float2(amx + bmy, amy - bmx);   // (a-c2) - i(b-d)
            else             u = make_float2(amx - bmy, amy + bmx);   // (a-c2) + i(b-d)
            sU[i] = u;
        }
        __syncthreads();
        float2 w1 = sTw[(8*c)&127];  w1.y = -w1.y;
        float2 w2 = sTw[(16*c)&127]; w2.y = -w2.y;
        float2 w3 = sTw[(24*c)&127]; w3.y = -w3.y;
        for (int i = tid; i < 8*KX; i += 256){
            int n2 = i / KX, kk = i - n2*KX;
            int b0 = n2*KX + kk;
            float2 u0 = sU[b0], u1 = sU[b0+8*KX], u2 = sU[b0+16*KX], u3 = sU[b0+24*KX];
            float2 t1 = cmul(u1,w1), t2 = cmul(u2,w2), t3 = cmul(u3,w3);
            float2 p = make_float2(u0.x+t2.x, u0.y+t2.y);
            float2 q = make_float2(u0.x-t2.x, u0.y-t2.y);
            float2 r = make_float2(t1.x+t3.x, t1.y+t3.y);
            float2 s = make_float2(t1.x-t3.x, t1.y-t3.y);
            sU[b0       ] = make_float2(p.x+r.x, p.y+r.y);   // s=0
            sU[b0+ 8*KX ] = make_float2(q.x+s.y, q.y-s.x);   // s=1: q - i s
            sU[b0+16*KX ] = make_float2(p.x-r.x, p.y-r.y);   // s=2
            sU[b0+24*KX ] = make_float2(q.x-s.y, q.y+s.x);   // s=3: q + i s
        }
        __syncthreads();
        for (int o = tid; o < 32*KX; o += 256){
            int m = o / KX, kk = o - m*KX;
            int ky = 4*m + c;
            int s4 = m & 3;
            const float2* v = &sU[(8*s4)*KX + kk];
            float ar0=0,ai0=0,ar1=0,ai1=0;
            int j = 0;
            #pragma unroll
            for (int n2 = 0; n2 < 8; n2 += 2){
                float2 v0 = v[n2*KX], v1 = v[(n2+1)*KX];
                float2 e0 = sTw[j]; int jn = (j + ky)&127;
                float2 e1 = sTw[jn];
                ar0 += v0.x*e0.x + v0.y*e0.y;  ai0 += v0.y*e0.x - v0.x*e0.y;
                ar1 += v1.x*e1.x + v1.y*e1.y;  ai1 += v1.y*e1.x - v1.x*e1.y;
                j = (jn + ky)&127;
            }
            A2[(z*DD + ky)*KX + kk] = make_float2(ar0+ar1, ai0+ai1);
        }
    } else {
        int o = (bid - 512)*256 + tid;
        if (o >= NB*DD*KX) return;
        int b = o / (DD*KX);
        int r = o - b*DD*KX;
        int h = r / KX, k = r - h*KX;
        int kky = (h + 64) & 127;
        const float2* col = B1 + b*DD*KX + k;
        float ar0=0,ai0=0,ar1=0,ai1=0,ar2=0,ai2=0,ar3=0,ai3=0;
        int i0=0, i1=kky&127, i2=(2*kky)&127, i3=(3*kky)&127;
        int st = (4*kky)&127;
        for (int y = 0; y < DD; y += 4){
            float2 v0=col[(y+0)*KX], v1=col[(y+1)*KX];
            float2 v2=col[(y+2)*KX], v3=col[(y+3)*KX];
            float2 e0=sTw[i0], e1=sTw[i1], e2=sTw[i2], e3=sTw[i3];
            ar0 += v0.x*e0.x + v0.y*e0.y;  ai0 += v0.y*e0.x - v0.x*e0.y;
            ar1 += v1.x*e1.x + v1.y*e1.y;  ai1 += v1.y*e1.x - v1.x*e1.y;
            ar2 += v2.x*e2.x + v2.y*e2.y;  ai2 += v2.y*e2.x - v2.x*e2.y;
            ar3 += v3.x*e3.x + v3.y*e3.y;  ai3 += v3.y*e3.x - v3.x*e3.y;
            i0=(i0+st)&127; i1=(i1+st)&127; i2=(i2+st)&127; i3=(i3+st)&127;
        }
        float sgn = ((h + k)&1) ? -1.f : 1.f;
        float cf = ctf[o];
        Fc[o] = make_float2((ar0+ar1+ar2+ar3)*sgn*cf, (ai0+ai1+ai2+ai3)*sgn*cf);
    }
}

// Stage D: fft along z (radix-4 x2) + (-1)^{hz+hy+k} + fftshift, then store
// fp16 pair into Yh: V[z][y] -> slot0 of cell (z,y), slot1 of cell (z,y-1).
__global__ __launch_bounds__(256) void k_volD(const float2* __restrict__ A2,
                       u32* __restrict__ Yh){
    __shared__ float2 sU[32*KX];
    __shared__ float2 sTw[128];
    int tid = threadIdx.x;
    int bid = blockIdx.x;
    int ky = bid >> 2, c = bid & 3;
    make_tw(sTw, tid);
    __syncthreads();

    const float2* base = A2 + ky*KX;
    for (int i = tid; i < 32*KX; i += 256){
        int n = i / KX, kk = i - n*KX;
        float2 a  = base[(n    )*DD*KX + kk];
        float2 bb = base[(n+32)*DD*KX + kk];
        float2 c2 = base[(n+64)*DD*KX + kk];
        float2 d  = base[(n+96)*DD*KX + kk];
        float acx = a.x + c2.x, acy = a.y + c2.y;
        float amx = a.x - c2.x, amy = a.y - c2.y;
        float bdx = bb.x + d.x, bdy = bb.y + d.y;
        float bmx = bb.x - d.x, bmy = bb.y - d.y;
        float2 u;
        if (c == 0)      u = make_float2(acx + bdx, acy + bdy);
        else if (c == 2) u = make_float2(acx - bdx, acy - bdy);
        else if (c == 1) u = make_float2(amx + bmy, amy - bmx);
        else             u = make_float2(amx - bmy, amy + bmx);
        sU[i] = u;
    }
    __syncthreads();
    float2 w1 = sTw[(8*c)&127];  w1.y = -w1.y;
    float2 w2 = sTw[(16*c)&127]; w2.y = -w2.y;
    float2 w3 = sTw[(24*c)&127]; w3.y = -w3.y;
    for (int i = tid; i < 8*KX; i += 256){
        int n2 = i / KX, kk = i - n2*KX;
        int b0 = n2*KX + kk;
        float2 u0 = sU[b0], u1 = sU[b0+8*KX], u2 = sU[b0+16*KX], u3 = sU[b0+24*KX];
        float2 t1 = cmul(u1,w1), t2 = cmul(u2,w2), t3 = cmul(u3,w3);
        float2 p = make_float2(u0.x+t2.x, u0.y+t2.y);
        float2 q = make_float2(u0.x-t2.x, u0.y-t2.y);
        float2 r = make_float2(t1.x+t3.x, t1.y+t3.y);
        float2 s = make_float2(t1.x-t3.x, t1.y-t3.y);
        sU[b0       ] = make_float2(p.x+r.x, p.y+r.y);
        sU[b0+ 8*KX ] = make_float2(q.x+s.y, q.y-s.x);
        sU[b0+16*KX ] = make_float2(p.x-r.x, p.y-r.y);
        sU[b0+24*KX ] = make_float2(q.x-s.y, q.y+s.x);
    }
    __syncthreads();
    int hy = (ky + 64) & 127;
    for (int o = tid; o < 32*KX; o += 256){
        int m = o / KX, kk = o - m*KX;
        int kz = 4*m + c;
        int hz = (kz + 64) & 127;
        int s4 = m & 3;
        const float2* v = &sU[(8*s4)*KX + kk];
        float ar0=0,ai0=0,ar1=0,ai1=0;
        int j = 0;
        #pragma unroll
        for (int n2 = 0; n2 < 8; n2 += 2){
            float2 v0 = v[n2*KX], v1 = v[(n2+1)*KX];
            float2 e0 = sTw[j]; int jn = (j + kz)&127;
            float2 e1 = sTw[jn];
            ar0 += v0.x*e0.x + v0.y*e0.y;  ai0 += v0.y*e0.x - v0.x*e0.y;
            ar1 += v1.x*e1.x + v1.y*e1.y;  ai1 += v1.y*e1.x - v1.x*e1.y;
            j = (jn + kz)&127;
        }
        float sgn = ((hz + hy + kk) & 1) ? -1.f : 1.f;
        __half2 hv = __floats2half2_rn((ar0+ar1)*sgn, (ai0+ai1)*sgn);
        u32 hp = *reinterpret_cast<u32*>(&hv);
        int z = hz + 1, y = hy + 1;
        Yh[2*((z*QY + y    )*QX + kk)    ] = hp;   // slot0 of (z,y)
        Yh[2*((z*QY + y - 1)*QX + kk) + 1] = hp;   // slot1 of (z,y-1)
    }
}

// trilinear gather + Fc product on the fp16 y-pair-packed volume.
// TWO 16B loads per point; interpolation fully in packed half2 math.
__device__ __forceinline__ float2 slice_point(const u32* __restrict__ Yh,
        float2 f, float xi, float zi, float yi){
    bool neg = xi < 0.f;
    if (neg){ xi = -xi; zi = 128.f - zi; yi = 128.f - yi; }
    xi = fminf(xi, 65.f);
    zi = fminf(fmaxf(zi, -1.f), 129.f);
    yi = fminf(fmaxf(yi, -1.f), 129.f);
    float zf = floorf(zi), yf = floorf(yi), xf = floorf(xi);
    float fz = zi - zf, fy = yi - yf, fx = xi - xf;
    int qi = (((int)zf + 1)*QY + ((int)yf + 1))*QX + (int)xf;
    uint4 A = *reinterpret_cast<const uint4*>(Yh + 2*qi);
    uint4 B = *reinterpret_cast<const uint4*>(Yh + 2*(qi + QPLANE));
    __half2 fxh = __float2half2_rn(fx);
    __half2 fyh = __float2half2_rn(fy);
    __half2 fzh = __float2half2_rn(fz);
    __half2 aL0 = *reinterpret_cast<const __half2*>(&A.x);   // (re,im) y0@x0 z0
    __half2 aH0 = *reinterpret_cast<const __half2*>(&A.y);   // y1@x0 z0
    __half2 aL1 = *reinterpret_cast<const __half2*>(&A.z);   // y0@x1 z0
    __half2 aH1 = *reinterpret_cast<const __half2*>(&A.w);   // y1@x1 z0
    __half2 bL0 = *reinterpret_cast<const __half2*>(&B.x);
    __half2 bH0 = *reinterpret_cast<const __half2*>(&B.y);
    __half2 bL1 = *reinterpret_cast<const __half2*>(&B.z);
    __half2 bH1 = *reinterpret_cast<const __half2*>(&B.w);
    __half2 a0 = __hfma2(fxh, __hsub2(aL1, aL0), aL0);
    __half2 a1 = __hfma2(fxh, __hsub2(aH1, aH0), aH0);
    __half2 b0 = __hfma2(fxh, __hsub2(bL1, bL0), bL0);
    __half2 b1 = __hfma2(fxh, __hsub2(bH1, bH0), bH0);
    __half2 c  = __hfma2(fyh, __hsub2(a1, a0), a0);
    __half2 d  = __hfma2(fyh, __hsub2(b1, b0), b0);
    __half2 s  = __hfma2(fzh, __hsub2(d, c), c);
    float2 sv = __half22float2(s);
    float sr = sv.x, si = sv.y;
    if (neg) si = -si;
    return make_float2(f.x*sr + f.y*si, f.y*sr - f.x*si);
}

// Main: XCD-swizzled; Nyquist tail + 4 chunks of Nk=16; radix-4 x2 in LDS;
// folded x-irfft; wave argmax; LAST block (atomic counter) runs the final
// top-2/mean/std/erf reduction for all batches.
__global__ __launch_bounds__(256,5) void k_main(
    const u32* __restrict__ Yh, const float2* __restrict__ Fc,
    const float* __restrict__ rotm, const float* __restrict__ grid,
    float* __restrict__ resVal, int2* __restrict__ resShift,
    float* __restrict__ out, int* __restrict__ cnt)
{
    __shared__ float2 sP[DD*16];      // 16384 B
    __shared__ float2 sT[WIN*KX];     // 12480 B
    __shared__ float2 sTw[128];       // 1024 B
    __shared__ float  sM[9];
    __shared__ float  swv[4];
    __shared__ int    swi[4];
    __shared__ int    sLast;

    int tid = threadIdx.x;
    int nb  = blockIdx.x;
    // bijective XCD swizzle: XCD (nb&7) processes orig-blocks [(nb&7)*125, ...)
    int blk = (nb & 7)*125 + (nb >> 3);
    int b  = blk / (NTT*NG);
    int rr = blk - b*NTT*NG;
    int t  = rr / NG;
    int g  = rr - t*NG;

    make_tw(sTw, tid);
    if (tid < 9){
        int i = tid/3, k = tid - 3*i;
        const float* R  = rotm + (b*NTT + t)*9;
        const float* Gm = grid + g*9;
        sM[tid] = R[i*3+0]*Gm[0*3+k] + R[i*3+1]*Gm[1*3+k] + R[i*3+2]*Gm[2*3+k];
    }
    __syncthreads();

    float M00=sM[0], M01=sM[1], M10=sM[3], M11=sM[4], M20=sM[6], M21=sM[7];
    const float2* FcB = Fc + b*DD*KX;

    // ---- Nyquist column k=64: direct 128-term y-IDFT ----
    if (tid < 128){
        int h = tid;
        float hf = (float)(h - 64);
        float xi = M01*hf + M00*64.f;
        float zi = M21*hf + M20*64.f + 64.f;
        float yi = M11*hf + M10*64.f + 64.f;
        sP[h] = slice_point(Yh, FcB[h*KX + 64], xi, zi, yi);
    }
    __syncthreads();
    if (tid < 96){
        int a = tid >> 2, p = tid & 3;
        int ry = (116 + a) & 127;
        int idx = (32*p*ry) & 127;
        float ar = 0.f, ai = 0.f;
        const float2* v = &sP[32*p];
        #pragma unroll 8
        for (int h2 = 0; h2 < 32; ++h2){
            float2 e = sTw[idx];
            float2 pv = v[h2];
            ar += pv.x*e.x - pv.y*e.y;
            ai += pv.x*e.y + pv.y*e.x;
            idx = (idx + ry) & 127;
        }
        sP[256 + tid] = make_float2(ar, ai);
    }
    __syncthreads();
    if (tid < 24){
        float2 p0 = sP[256 + tid*4 + 0];
        float2 p1 = sP[256 + tid*4 + 1];
        float2 p2 = sP[256 + tid*4 + 2];
        float2 p3 = sP[256 + tid*4 + 3];
        float sg = (tid & 1) ? -(1.f/128.f) : (1.f/128.f);
        sT[tid*KX + 64] = make_float2((p0.x+p1.x+p2.x+p3.x)*sg,
                                      (p0.y+p1.y+p2.y+p3.y)*sg);
    }
    __syncthreads();

    // ---- 4 chunks of 16 k-columns ----
    const int kk = tid & 15;
    const int h0 = tid >> 4;
    const float hf0 = (float)(h0 - 64);
    const float dxi = 16.f*M01, dzi = 16.f*M21, dyi = 16.f*M11;

    for (int cc = 0; cc < 4; ++cc){
        int w = cc*16 + kk;
        float wf = (float)w;
        float xi0 = M01*hf0 + M00*wf;
        float zi0 = M21*hf0 + M20*wf + 64.f;
        float yi0 = M11*hf0 + M10*wf + 64.f;
        int fidx = h0*KX + w;

        // Phase 1: 8 points per thread, incremental coords
        #pragma unroll 2
        for (int j = 0; j < 8; ++j){
            sP[tid + 256*j] = slice_point(Yh, FcB[fidx], xi0, zi0, yi0);
            xi0 += dxi; zi0 += dzi; yi0 += dyi; fidx += 16*KX;
        }
        __syncthreads();

        // Level 1 (inverse): identity indexing
        #pragma unroll
        for (int rep = 0; rep < 2; ++rep){
            int i = tid + 256*rep;
            float2 a  = sP[i];
            float2 bb = sP[i + 512];
            float2 c2 = sP[i + 1024];
            float2 d  = sP[i + 1536];
            float acx = a.x + c2.x, acy = a.y + c2.y;
            float amx = a.x - c2.x, amy = a.y - c2.y;
            float bdx = bb.x + d.x, bdy = bb.y + d.y;
            float bmx = bb.x - d.x, bmy = bb.y - d.y;
            sP[i       ] = make_float2(acx + bdx, acy + bdy);   // c=0
            sP[i + 512 ] = make_float2(amx - bmy, amy + bmx);   // c=1: + i(b-d)
            sP[i + 1024] = make_float2(acx - bdx, acy - bdy);   // c=2
            sP[i + 1536] = make_float2(amx + bmy, amy - bmx);   // c=3: - i(b-d)
        }
        __syncthreads();

        // Level 2 (inverse, in place)
        #pragma unroll
        for (int rep = 0; rep < 2; ++rep){
            int i = tid + 256*rep;
            int c = i >> 7, r7 = i & 127;
            int b0 = (c << 9) + r7;
            float2 u0 = sP[b0], u1 = sP[b0+128], u2 = sP[b0+256], u3 = sP[b0+384];
            float2 w1 = sTw[(8*c)&127], w2 = sTw[(16*c)&127], w3 = sTw[(24*c)&127];
            float2 t1 = cmul(u1,w1), t2 = cmul(u2,w2), t3 = cmul(u3,w3);
            float2 p  = make_float2(u0.x+t2.x, u0.y+t2.y);
            float2 qq = make_float2(u0.x-t2.x, u0.y-t2.y);
            float2 r  = make_float2(t1.x+t3.x, t1.y+t3.y);
            float2 s  = make_float2(t1.x-t3.x, t1.y-t3.y);
            sP[b0      ] = make_float2(p.x+r.x,  p.y+r.y);    // s=0
            sP[b0 + 128] = make_float2(qq.x-s.y, qq.y+s.x);   // s=1: q + i s
            sP[b0 + 256] = make_float2(p.x-r.x,  p.y-r.y);    // s=2
            sP[b0 + 384] = make_float2(qq.x+s.y, qq.y-s.x);   // s=3: q - i s
        }
        __syncthreads();

        // Phase 2: 8-term y-IDFT (384 items)
        for (int o = tid; o < 24*16; o += 256){
            int a = o >> 4, kx = o & 15;
            int ry = (116 + a) & 127;
            int c = ry & 3, s4 = (ry >> 2) & 3;
            const float2* v = &sP[(c << 9) + (s4 << 7) + kx];
            float ar0=0,ai0=0,ar1=0,ai1=0;
            int j2 = 0;
            #pragma unroll
            for (int n2 = 0; n2 < 8; n2 += 2){
                float2 v0 = v[n2*16], v1 = v[(n2+1)*16];
                float2 e0 = sTw[j2]; int jn = (j2 + ry)&127;
                float2 e1 = sTw[jn];
                ar0 += v0.x*e0.x - v0.y*e0.y;  ai0 += v0.x*e0.y + v0.y*e0.x;
                ar1 += v1.x*e1.x - v1.y*e1.y;  ai1 += v1.x*e1.y + v1.y*e1.x;
                j2 = (jn + ry)&127;
            }
            float sg = (a & 1) ? -(1.f/128.f) : (1.f/128.f);   // (-1)^ry / 128
            sT[a*KX + cc*16 + kx] = make_float2((ar0+ar1)*sg, (ai0+ai1)*sg);
        }
        __syncthreads();
    }

    // Phase 3a: Hermitian fold into sP (free): Ae (even rx) / Ao (odd rx)
    float2* sPf = sP;
    for (int o = tid; o < WIN*31; o += 256){
        int a = o / 31, km1 = o - a*31;
        int k = km1 + 1;
        const float2* Trow = &sT[a*KX];
        float2 T1 = Trow[k], T2 = Trow[64-k];
        sPf[a*31 + km1]       = make_float2(T1.x + T2.x, T1.y - T2.y);
        sPf[744 + a*31 + km1] = make_float2(T1.x - T2.x, T1.y + T2.y);
    }
    __syncthreads();

    // Phase 3b: 31-term folded x-irfft on the 24x24 window
    float* sC = reinterpret_cast<float*>(sP + 1488);
    for (int o = tid; o < WIN*WIN; o += 256){
        int a = o / WIN, bx = o - a*WIN;
        int rx = (116 + bx) & 127;
        const float2* Trow = &sT[a*KX];
        float2 T32 = Trow[32];
        float base = Trow[0].x + ((bx & 1) ? -Trow[64].x : Trow[64].x);
        int r4 = rx & 3;
        base += (r4==0) ?  2.f*T32.x : (r4==1) ? -2.f*T32.y
              : (r4==2) ? -2.f*T32.x :  2.f*T32.y;
        const float2* A = sPf + ((bx & 1) ? 744 : 0) + a*31 - 1;  // A[k], k=1..31
        float acc0 = 0.f, acc1 = 0.f;
        int j1 = rx, j2 = (2*rx)&127;
        int st = (2*rx)&127;
        for (int k = 1; k < 31; k += 2){
            float2 e1 = sTw[j1]; float2 A1v = A[k];
            float2 e2 = sTw[j2]; float2 A2v = A[k+1];
            acc0 += A1v.x*e1.x - A1v.y*e1.y;
            acc1 += A2v.x*e2.x - A2v.y*e2.y;
            j1=(j1+st)&127; j2=(j2+st)&127;
        }
        {
            float2 e = sTw[(31*rx)&127]; float2 Av = A[31];
            acc0 += Av.x*e.x - Av.y*e.y;
        }
        sC[o] = (base + 2.f*(acc0+acc1))*(1.f/128.f);
    }
    __syncthreads();

    // Phase 4: argmax, row-major first occurrence — wave shfl_xor reduce
    float best = -FLT_MAX; int bidx = 0x7fffffff;
    for (int i = tid; i < WIN*WIN; i += 256){
        float v = sC[i];
        if (v > best){ best = v; bidx = i; }
    }
    #pragma unroll
    for (int s = 32; s > 0; s >>= 1){
        float ov = __shfl_xor(best, s, 64);
        int   oi = __shfl_xor(bidx, s, 64);
        if (ov > best || (ov == best && oi < bidx)){ best = ov; bidx = oi; }
    }
    if ((tid & 63) == 0){ swv[tid>>6] = best; swi[tid>>6] = bidx; }
    __syncthreads();
    if (tid == 0){
        float bv = swv[0]; int bi = swi[0];
        #pragma unroll
        for (int w2 = 1; w2 < 4; ++w2){
            if (swv[w2] > bv || (swv[w2] == bv && swi[w2] < bi)){ bv = swv[w2]; bi = swi[w2]; }
        }
        int a = bi / WIN, bx = bi - a*WIN;
        resVal[blk] = bv;
        resShift[blk] = make_int2(H0 + bx, H0 + a);
        __threadfence();
        int prev = atomicAdd(cnt, 1);
        sLast = (prev == NBTG - 1) ? 1 : 0;
    }
    __syncthreads();

    // ---- LAST block: final top-2 / mean / std / erf for all batches ----
    if (sLast){
        __threadfence();
        float* sv   = reinterpret_cast<float*>(sP);
        int*   sidx = reinterpret_cast<int*>(sP) + 256;
        float* sr   = reinterpret_cast<float*>(sP) + 512;
        const int N = NTT*NG;   // 250
        for (int bb = 0; bb < NB; ++bb){
            const float* v = resVal + bb*N;
            float myv = (tid < N) ? v[tid] : -FLT_MAX;

            sv[tid] = myv; sidx[tid] = (tid < N) ? tid : 0x7fffffff;
            __syncthreads();
            for (int s = 128; s > 0; s >>= 1){
                if (tid < s){
                    float v2 = sv[tid+s]; int i2 = sidx[tid+s];
                    if (v2 > sv[tid] || (v2 == sv[tid] && i2 < sidx[tid])){ sv[tid]=v2; sidx[tid]=i2; }
                }
                __syncthreads();
            }
            float v0 = sv[0]; int i0 = sidx[0];
            __syncthreads();

            bool act = (tid < N) && (tid != i0);
            sv[tid] = act ? myv : -FLT_MAX; sidx[tid] = act ? tid : 0x7fffffff;
            __syncthreads();
            for (int s = 128; s > 0; s >>= 1){
                if (tid < s){
                    float v2 = sv[tid+s]; int i2 = sidx[tid+s];
                    if (v2 > sv[tid] || (v2 == sv[tid] && i2 < sidx[tid])){ sv[tid]=v2; sidx[tid]=i2; }
                }
                __syncthreads();
            }
            float v1 = sv[0]; int i1 = sidx[0];
            __syncthreads();

            sr[tid] = (tid < N) ? myv : 0.f;
            __syncthreads();
            for (int s = 128; s > 0; s >>= 1){
                if (tid < s) sr[tid] += sr[tid+s];
                __syncthreads();
            }
            float mean = sr[0] / (float)N;
            __syncthreads();

            float dd = (tid < N) ? (myv - mean) : 0.f;
            sr[tid] = dd*dd;
            __syncthreads();
            for (int s = 128; s > 0; s >>= 1){
                if (tid < s) sr[tid] += sr[tid+s];
                __syncthreads();
            }

            if (tid == 0){
                float stdv = sqrtf(sr[0] / (float)(N - 1));
                float vals[2] = {v0, v1};
                int   idxs[2] = {i0, i1};
                for (int k2 = 0; k2 < 2; ++k2){
                    out[bb*2 + k2] = vals[k2];
                    int gi = idxs[k2] % NG;
                    for (int j = 0; j < 9; ++j) out[8 + (bb*2+k2)*9 + j] = grid[gi*9 + j];
                    int2 sh = resShift[bb*N + idxs[k2]];
                    out[80 + (bb*2+k2)*2 + 0] = -((float)sh.x - 64.f)*1.5f;
                    out[80 + (bb*2+k2)*2 + 1] = -((float)sh.y - 64.f)*1.5f;
                    out[96 + bb*2 + k2] = 0.5f*(1.f + erff((vals[k2] - mean)/(stdv*1.41421356237309515f)));
                }
            }
            __syncthreads();
        }
    }
}

extern "C" void kernel_launch(void* const* d_in, const int* in_sizes, int n_in,
                              void* d_out, int out_size, void* d_ws, size_t ws_size,
                              hipStream_t stream)
{
    const float* vol  = (const float*)d_in[0];
    const float* imgs = (const float*)d_in[1];
    const float* ctf  = (const float*)d_in[2];
    const float* rotm = (const float*)d_in[3];
    const float* grid = (const float*)d_in[4];
    float* out = (float*)d_out;

    const size_t YH_BYTES  = (size_t)QN*8;                      // 9,406,848
    const size_t A1_BYTES  = (size_t)DD*DD*KX*sizeof(float2);   // 8,519,680
    const size_t B1_BYTES  = (size_t)NB*DD*KX*sizeof(float2);   //   266,240

    char* ws = (char*)d_ws;
    // Yh is NOT aliased (zeroed concurrently with stageA's FFT blocks)
    u32*    Yh = (u32*)(ws);
    size_t off = YH_BYTES;
    float2* A1 = (float2*)(ws + off); off += A1_BYTES;
    float2* B1 = (float2*)(ws + off); off += B1_BYTES;
    float2* A2 = (float2*)(ws + off); off += A1_BYTES;
    float2* Fc = (float2*)(ws + off); off += B1_BYTES;
    float* resVal = (float*)(ws + off); off += (size_t)NBTG*sizeof(float);
    int2* resShift = (int2*)(ws + off); off += (size_t)NBTG*sizeof(int2);
    int* cnt = (int*)(ws + off); off += sizeof(int);

    const int n4 = (int)(YH_BYTES / 16);   // uint4 count
    k_stageA<<<898, 256, 0, stream>>>(vol, imgs, A1, B1, (uint4*)Yh, n4, cnt);
    k_stageB<<<642, 256, 0, stream>>>(A1, ctf, B1, A2, Fc);
    k_volD  <<<512, 256, 0, stream>>>(A2, Yh);
    k_main  <<<NBTG,256, 0, stream>>>(Yh, Fc, rotm, grid, resVal, resShift, out, cnt);
}

// Round 17
// 99.583 us; speedup vs baseline: 1.3455x; 1.3455x over previous
//
#include <hip/hip_runtime.h>
#include <hip/hip_fp16.h>
#include <math.h>
#include <float.h>

#define DD   128
#define KX   65          // D/2+1
#define NB   4
#define NTT  2
#define NG   125
#define NBTG (NB*NTT*NG) // 1000
#define WIN  24
#define H0   52

// fp16 y-pair-packed padded volume: cell (z,y,x) = 8B, 4 halves:
// (re V[z][y][x], im V[z][y][x], re V[z][y+1][x], im V[z][y+1][x])
// z in [0,131], y in [0,130], x in [0,67]; V-interior at z,y in [1,128]
#define QZ  132
#define QY  131
#define QX  68
#define QPLANE (QY*QX)      // 8908
#define QN  (QZ*QY*QX)      // 1,175,856 cells (8B each)

typedef unsigned int u32;

__device__ __forceinline__ float2 cmul(float2 a, float2 b){
    return make_float2(a.x*b.x - a.y*b.y, a.x*b.y + a.y*b.x);
}

// inline twiddle table: sTw[m] = e^{+2*pi*i*m/128}
__device__ __forceinline__ void make_tw(float2* sTw, int tid){
    if (tid < 128){
        float s, c;
        sincosf((float)tid * (float)(M_PI/64.0), &s, &c);
        sTw[tid] = make_float2(c, s);
    }
}

// Stage A (fused): bid<512 -> vol rfft-x via 2-real-rows-as-complex +
// radix-4 x2 levels + 8-term dots + Hermitian unpack (sinc^2 via LDS table);
// 512<=bid<642 -> image rfft-x; bid>=642 -> zero the packed fp16 volume.
__global__ __launch_bounds__(256) void k_stageA(const float* __restrict__ vol,
                       const float* __restrict__ imgs,
                       float2* __restrict__ A1, float2* __restrict__ B1,
                       uint4* __restrict__ Yz, int n4){
    __shared__ float2 sZ [16*DD];   // 16 KB
    __shared__ float2 sZ2[16*DD];   // 16 KB
    __shared__ float2 sTw[128];
    __shared__ float  sSinc[257];
    int tid = threadIdx.x;
    int bid = blockIdx.x;

    if (bid >= 642){
        int i = (bid - 642)*256 + tid;
        for (; i < n4; i += 256*256)
            Yz[i] = make_uint4(0,0,0,0);
        return;
    }
    make_tw(sTw, tid);

    if (bid < 512){
        // sinc^2 table over t = r^2 in [0, 0.75]
        for (int i = tid; i < 257; i += 256){
            float t = (float)i * (0.75f/256.f);
            float r = sqrtf(t);
            float s = (r > 0.f) ? (sinf((float)M_PI*r)/((float)M_PI*r)) : 1.f;
            sSinc[i] = s*s;
        }
        __syncthreads();
        int z = bid >> 2, q = bid & 3;
        int y0 = q*32;
        float fz = (z-64)*(1.0f/128.0f);
        float fz2 = fz*fz;
        for (int i = tid; i < 16*DD; i += 256){
            int p = i >> 7, x = i & 127;
            int yA = y0 + 2*p;
            float fx = (x-64)*(1.0f/128.0f);
            float fyA = (yA-64)*(1.0f/128.0f);
            float fyB = fyA + (1.0f/128.0f);
            float b2 = fz2 + fx*fx;
            float tA = (b2 + fyA*fyA) * (256.f/0.75f);
            float tB = (b2 + fyB*fyB) * (256.f/0.75f);
            int iA = min((int)tA, 255), iB = min((int)tB, 255);
            float frA = tA - (float)iA, frB = tB - (float)iB;
            float wA = sSinc[iA] + frA*(sSinc[iA+1]-sSinc[iA]);
            float wB = sSinc[iB] + frB*(sSinc[iB+1]-sSinc[iB]);
            float a = vol[(z*DD + yA)*DD + x] * wA;
            float b = vol[(z*DD + yA+1)*DD + x] * wB;
            sZ[i] = make_float2(a, b);
        }
        __syncthreads();
        // level 1 (forward)
        for (int i = tid; i < 16*32; i += 256){
            int p = i >> 5, x1 = i & 31;
            int b0 = p*DD + x1;
            float2 a = sZ[b0], bb = sZ[b0+32], c2 = sZ[b0+64], d = sZ[b0+96];
            float acx=a.x+c2.x, acy=a.y+c2.y;
            float amx=a.x-c2.x, amy=a.y-c2.y;
            float bdx=bb.x+d.x, bdy=bb.y+d.y;
            float bmx=bb.x-d.x, bmy=bb.y-d.y;
            sZ[b0   ] = make_float2(acx+bdx, acy+bdy);     // c=0
            sZ[b0+32] = make_float2(amx+bmy, amy-bmx);     // c=1: (a-c2)-i(b-d)
            sZ[b0+64] = make_float2(acx-bdx, acy-bdy);     // c=2
            sZ[b0+96] = make_float2(amx-bmy, amy+bmx);     // c=3: +i(b-d)
        }
        __syncthreads();
        // level 2 (forward, in place)
        for (int i = tid; i < 16*32; i += 256){
            int p = i >> 5, r5 = i & 31;
            int c = r5 >> 3, x2 = r5 & 7;
            int b0 = p*DD + 32*c + x2;
            float2 u0 = sZ[b0], u1 = sZ[b0+8], u2 = sZ[b0+16], u3 = sZ[b0+24];
            float2 w1 = sTw[(8*c)&127];  w1.y = -w1.y;
            float2 w2 = sTw[(16*c)&127]; w2.y = -w2.y;
            float2 w3 = sTw[(24*c)&127]; w3.y = -w3.y;
            float2 t1 = cmul(u1,w1), t2 = cmul(u2,w2), t3 = cmul(u3,w3);
            float2 pp = make_float2(u0.x+t2.x, u0.y+t2.y);
            float2 qq = make_float2(u0.x-t2.x, u0.y-t2.y);
            float2 rr = make_float2(t1.x+t3.x, t1.y+t3.y);
            float2 ss = make_float2(t1.x-t3.x, t1.y-t3.y);
            sZ[b0   ] = make_float2(pp.x+rr.x, pp.y+rr.y);   // s=0
            sZ[b0+8 ] = make_float2(qq.x+ss.y, qq.y-ss.x);   // s=1: q - i s
            sZ[b0+16] = make_float2(pp.x-rr.x, pp.y-rr.y);   // s=2
            sZ[b0+24] = make_float2(qq.x-ss.y, qq.y+ss.x);   // s=3: q + i s
        }
        __syncthreads();
        // 8-term dots
        for (int i = tid; i < 16*DD; i += 256){
            int p = i >> 7, k = i & 127;
            int c = k & 3, s = (k >> 2) & 3;
            const float2* v = &sZ[p*DD + 32*c + 8*s];
            float ar0=0,ai0=0,ar1=0,ai1=0;
            int j = 0;
            #pragma unroll
            for (int x2 = 0; x2 < 8; x2 += 2){
                float2 v0 = v[x2], v1 = v[x2+1];
                float2 e0 = sTw[j]; int jn = (j + k)&127;
                float2 e1 = sTw[jn];
                ar0 += v0.x*e0.x + v0.y*e0.y;  ai0 += v0.y*e0.x - v0.x*e0.y;
                ar1 += v1.x*e1.x + v1.y*e1.y;  ai1 += v1.y*e1.x - v1.x*e1.y;
                j = (jn + k)&127;
            }
            sZ2[i] = make_float2(ar0+ar1, ai0+ai1);
        }
        __syncthreads();
        // Hermitian unpack
        for (int i = tid; i < 16*KX; i += 256){
            int p = i / KX, k = i - p*KX;
            float2 Zk = sZ2[p*DD + k];
            float2 Zm = sZ2[p*DD + ((128-k)&127)];
            float2 A = make_float2(0.5f*(Zk.x+Zm.x), 0.5f*(Zk.y-Zm.y));
            float Dx = Zk.x - Zm.x, Dy = Zk.y + Zm.y;
            float2 Bv = make_float2(0.5f*Dy, -0.5f*Dx);
            int yA = y0 + 2*p;
            A1[(z*DD + yA  )*KX + k] = A;
            A1[(z*DD + yA+1)*KX + k] = Bv;
        }
    } else {
        __syncthreads();
        int o = (bid - 512)*256 + tid;
        if (o >= NB*DD*KX) return;
        int b = o / (DD*KX);
        int r = o - b*DD*KX;
        int y = r / KX, k = r - y*KX;
        const float* row = imgs + (b*DD + y)*DD;
        float ar0=0,ai0=0,ar1=0,ai1=0,ar2=0,ai2=0,ar3=0,ai3=0;
        int i0=0, i1=k&127, i2=(2*k)&127, i3=(3*k)&127;
        int st = (4*k)&127;
        for (int x = 0; x < DD; x += 4){
            float v0=row[x], v1=row[x+1], v2=row[x+2], v3=row[x+3];
            float2 e0=sTw[i0], e1=sTw[i1], e2=sTw[i2], e3=sTw[i3];
            ar0 += v0*e0.x; ai0 -= v0*e0.y;
            ar1 += v1*e1.x; ai1 -= v1*e1.y;
            ar2 += v2*e2.x; ai2 -= v2*e2.y;
            ar3 += v3*e3.x; ai3 -= v3*e3.y;
            i0=(i0+st)&127; i1=(i1+st)&127; i2=(i2+st)&127; i3=(i3+st)&127;
        }
        B1[o] = make_float2(ar0+ar1+ar2+ar3, ai0+ai1+ai2+ai3);
    }
}

// Stage B (fused): bid<512 -> vol fft-y radix-4 x2 levels (class per block);
//                  bid>=512 -> image fft-y + signs + ctf premul -> Fc.
__global__ __launch_bounds__(256) void k_stageB(const float2* __restrict__ A1,
                       const float* __restrict__ ctf, const float2* __restrict__ B1,
                       float2* __restrict__ A2, float2* __restrict__ Fc){
    __shared__ float2 sU[32*KX];   // 16640 B
    __shared__ float2 sTw[128];
    int tid = threadIdx.x;
    int bid = blockIdx.x;
    make_tw(sTw, tid);
    __syncthreads();

    if (bid < 512){
        int z = bid >> 2, c = bid & 3;
        const float2* base = A1 + z*DD*KX;
        for (int i = tid; i < 32*KX; i += 256){
            int n = i / KX, kk = i - n*KX;
            float2 a  = base[(n    )*KX + kk];
            float2 bb = base[(n+32)*KX + kk];
            float2 c2 = base[(n+64)*KX + kk];
            float2 d  = base[(n+96)*KX + kk];
            float acx = a.x + c2.x, acy = a.y + c2.y;
            float amx = a.x - c2.x, amy = a.y - c2.y;
            float bdx = bb.x + d.x, bdy = bb.y + d.y;
            float bmx = bb.x - d.x, bmy = bb.y - d.y;
            float2 u;
            if (c == 0)      u = make_float2(acx + bdx, acy + bdy);
            else if (c == 2) u = make_float2(acx - bdx, acy - bdy);
            else if (c == 1) u = make_float2(amx + bmy, amy - bmx);   // (a-c2) - i(b-d)
            else             u = make_float2(amx - bmy, amy + bmx);   // (a-c2) + i(b-d)
            sU[i] = u;
        }
        __syncthreads();
        float2 w1 = sTw[(8*c)&127];  w1.y = -w1.y;
        float2 w2 = sTw[(16*c)&127]; w2.y = -w2.y;
        float2 w3 = sTw[(24*c)&127]; w3.y = -w3.y;
        for (int i = tid; i < 8*KX; i += 256){
            int n2 = i / KX, kk = i - n2*KX;
            int b0 = n2*KX + kk;
            float2 u0 = sU[b0], u1 = sU[b0+8*KX], u2 = sU[b0+16*KX], u3 = sU[b0+24*KX];
            float2 t1 = cmul(u1,w1), t2 = cmul(u2,w2), t3 = cmul(u3,w3);
            float2 p = make_float2(u0.x+t2.x, u0.y+t2.y);
            float2 q = make_float2(u0.x-t2.x, u0.y-t2.y);
            float2 r = make_float2(t1.x+t3.x, t1.y+t3.y);
            float2 s = make_float2(t1.x-t3.x, t1.y-t3.y);
            sU[b0       ] = make_float2(p.x+r.x, p.y+r.y);   // s=0
            sU[b0+ 8*KX ] = make_float2(q.x+s.y, q.y-s.x);   // s=1: q - i s
            sU[b0+16*KX ] = make_float2(p.x-r.x, p.y-r.y);   // s=2
            sU[b0+24*KX ] = make_float2(q.x-s.y, q.y+s.x);   // s=3: q + i s
        }
        __syncthreads();
        for (int o = tid; o < 32*KX; o += 256){
            int m = o / KX, kk = o - m*KX;
            int ky = 4*m + c;
            int s4 = m & 3;
            const float2* v = &sU[(8*s4)*KX + kk];
            float ar0=0,ai0=0,ar1=0,ai1=0;
            int j = 0;
            #pragma unroll
            for (int n2 = 0; n2 < 8; n2 += 2){
                float2 v0 = v[n2*KX], v1 = v[(n2+1)*KX];
                float2 e0 = sTw[j]; int jn = (j + ky)&127;
                float2 e1 = sTw[jn];
                ar0 += v0.x*e0.x + v0.y*e0.y;  ai0 += v0.y*e0.x - v0.x*e0.y;
                ar1 += v1.x*e1.x + v1.y*e1.y;  ai1 += v1.y*e1.x - v1.x*e1.y;
                j = (jn + ky)&127;
            }
            A2[(z*DD + ky)*KX + kk] = make_float2(ar0+ar1, ai0+ai1);
        }
    } else {
        int o = (bid - 512)*256 + tid;
        if (o >= NB*DD*KX) return;
        int b = o / (DD*KX);
        int r = o - b*DD*KX;
        int h = r / KX, k = r - h*KX;
        int kky = (h + 64) & 127;
        const float2* col = B1 + b*DD*KX + k;
        float ar0=0,ai0=0,ar1=0,ai1=0,ar2=0,ai2=0,ar3=0,ai3=0;
        int i0=0, i1=kky&127, i2=(2*kky)&127, i3=(3*kky)&127;
        int st = (4*kky)&127;
        for (int y = 0; y < DD; y += 4){
            float2 v0=col[(y+0)*KX], v1=col[(y+1)*KX];
            float2 v2=col[(y+2)*KX], v3=col[(y+3)*KX];
            float2 e0=sTw[i0], e1=sTw[i1], e2=sTw[i2], e3=sTw[i3];
            ar0 += v0.x*e0.x + v0.y*e0.y;  ai0 += v0.y*e0.x - v0.x*e0.y;
            ar1 += v1.x*e1.x + v1.y*e1.y;  ai1 += v1.y*e1.x - v1.x*e1.y;
            ar2 += v2.x*e2.x + v2.y*e2.y;  ai2 += v2.y*e2.x - v2.x*e2.y;
            ar3 += v3.x*e3.x + v3.y*e3.y;  ai3 += v3.y*e3.x - v3.x*e3.y;
            i0=(i0+st)&127; i1=(i1+st)&127; i2=(i2+st)&127; i3=(i3+st)&127;
        }
        float sgn = ((h + k)&1) ? -1.f : 1.f;
        float cf = ctf[o];
        Fc[o] = make_float2((ar0+ar1+ar2+ar3)*sgn*cf, (ai0+ai1+ai2+ai3)*sgn*cf);
    }
}

// Stage D: fft along z (radix-4 x2) + (-1)^{hz+hy+k} + fftshift, then store
// fp16 pair into Yh: V[z][y] -> slot0 of cell (z,y), slot1 of cell (z,y-1).
__global__ __launch_bounds__(256) void k_volD(const float2* __restrict__ A2,
                       u32* __restrict__ Yh){
    __shared__ float2 sU[32*KX];
    __shared__ float2 sTw[128];
    int tid = threadIdx.x;
    int bid = blockIdx.x;
    int ky = bid >> 2, c = bid & 3;
    make_tw(sTw, tid);
    __syncthreads();

    const float2* base = A2 + ky*KX;
    for (int i = tid; i < 32*KX; i += 256){
        int n = i / KX, kk = i - n*KX;
        float2 a  = base[(n    )*DD*KX + kk];
        float2 bb = base[(n+32)*DD*KX + kk];
        float2 c2 = base[(n+64)*DD*KX + kk];
        float2 d  = base[(n+96)*DD*KX + kk];
        float acx = a.x + c2.x, acy = a.y + c2.y;
        float amx = a.x - c2.x, amy = a.y - c2.y;
        float bdx = bb.x + d.x, bdy = bb.y + d.y;
        float bmx = bb.x - d.x, bmy = bb.y - d.y;
        float2 u;
        if (c == 0)      u = make_float2(acx + bdx, acy + bdy);
        else if (c == 2) u = make_float2(acx - bdx, acy - bdy);
        else if (c == 1) u = make_float2(amx + bmy, amy - bmx);
        else             u = make_float2(amx - bmy, amy + bmx);
        sU[i] = u;
    }
    __syncthreads();
    float2 w1 = sTw[(8*c)&127];  w1.y = -w1.y;
    float2 w2 = sTw[(16*c)&127]; w2.y = -w2.y;
    float2 w3 = sTw[(24*c)&127]; w3.y = -w3.y;
    for (int i = tid; i < 8*KX; i += 256){
        int n2 = i / KX, kk = i - n2*KX;
        int b0 = n2*KX + kk;
        float2 u0 = sU[b0], u1 = sU[b0+8*KX], u2 = sU[b0+16*KX], u3 = sU[b0+24*KX];
        float2 t1 = cmul(u1,w1), t2 = cmul(u2,w2), t3 = cmul(u3,w3);
        float2 p = make_float2(u0.x+t2.x, u0.y+t2.y);
        float2 q = make_float2(u0.x-t2.x, u0.y-t2.y);
        float2 r = make_float2(t1.x+t3.x, t1.y+t3.y);
        float2 s = make_float2(t1.x-t3.x, t1.y-t3.y);
        sU[b0       ] = make_float2(p.x+r.x, p.y+r.y);
        sU[b0+ 8*KX ] = make_float2(q.x+s.y, q.y-s.x);
        sU[b0+16*KX ] = make_float2(p.x-r.x, p.y-r.y);
        sU[b0+24*KX ] = make_float2(q.x-s.y, q.y+s.x);
    }
    __syncthreads();
    int hy = (ky + 64) & 127;
    for (int o = tid; o < 32*KX; o += 256){
        int m = o / KX, kk = o - m*KX;
        int kz = 4*m + c;
        int hz = (kz + 64) & 127;
        int s4 = m & 3;
        const float2* v = &sU[(8*s4)*KX + kk];
        float ar0=0,ai0=0,ar1=0,ai1=0;
        int j = 0;
        #pragma unroll
        for (int n2 = 0; n2 < 8; n2 += 2){
            float2 v0 = v[n2*KX], v1 = v[(n2+1)*KX];
            float2 e0 = sTw[j]; int jn = (j + kz)&127;
            float2 e1 = sTw[jn];
            ar0 += v0.x*e0.x + v0.y*e0.y;  ai0 += v0.y*e0.x - v0.x*e0.y;
            ar1 += v1.x*e1.x + v1.y*e1.y;  ai1 += v1.y*e1.x - v1.x*e1.y;
            j = (jn + kz)&127;
        }
        float sgn = ((hz + hy + kk) & 1) ? -1.f : 1.f;
        __half2 hv = __floats2half2_rn((ar0+ar1)*sgn, (ai0+ai1)*sgn);
        u32 hp = *reinterpret_cast<u32*>(&hv);
        int z = hz + 1, y = hy + 1;
        Yh[2*((z*QY + y    )*QX + kk)    ] = hp;   // slot0 of (z,y)
        Yh[2*((z*QY + y - 1)*QX + kk) + 1] = hp;   // slot1 of (z,y-1)
    }
}

// trilinear gather + Fc product on the fp16 y-pair-packed volume.
// TWO 16B loads per point; interpolation fully in packed half2 math.
__device__ __forceinline__ float2 slice_point(const u32* __restrict__ Yh,
        float2 f, float xi, float zi, float yi){
    bool neg = xi < 0.f;
    if (neg){ xi = -xi; zi = 128.f - zi; yi = 128.f - yi; }
    xi = fminf(xi, 65.f);
    zi = fminf(fmaxf(zi, -1.f), 129.f);
    yi = fminf(fmaxf(yi, -1.f), 129.f);
    float zf = floorf(zi), yf = floorf(yi), xf = floorf(xi);
    float fz = zi - zf, fy = yi - yf, fx = xi - xf;
    int qi = (((int)zf + 1)*QY + ((int)yf + 1))*QX + (int)xf;
    uint4 A = *reinterpret_cast<const uint4*>(Yh + 2*qi);
    uint4 B = *reinterpret_cast<const uint4*>(Yh + 2*(qi + QPLANE));
    __half2 fxh = __float2half2_rn(fx);
    __half2 fyh = __float2half2_rn(fy);
    __half2 fzh = __float2half2_rn(fz);
    __half2 aL0 = *reinterpret_cast<const __half2*>(&A.x);   // (re,im) y0@x0 z0
    __half2 aH0 = *reinterpret_cast<const __half2*>(&A.y);   // y1@x0 z0
    __half2 aL1 = *reinterpret_cast<const __half2*>(&A.z);   // y0@x1 z0
    __half2 aH1 = *reinterpret_cast<const __half2*>(&A.w);   // y1@x1 z0
    __half2 bL0 = *reinterpret_cast<const __half2*>(&B.x);
    __half2 bH0 = *reinterpret_cast<const __half2*>(&B.y);
    __half2 bL1 = *reinterpret_cast<const __half2*>(&B.z);
    __half2 bH1 = *reinterpret_cast<const __half2*>(&B.w);
    __half2 a0 = __hfma2(fxh, __hsub2(aL1, aL0), aL0);
    __half2 a1 = __hfma2(fxh, __hsub2(aH1, aH0), aH0);
    __half2 b0 = __hfma2(fxh, __hsub2(bL1, bL0), bL0);
    __half2 b1 = __hfma2(fxh, __hsub2(bH1, bH0), bH0);
    __half2 c  = __hfma2(fyh, __hsub2(a1, a0), a0);
    __half2 d  = __hfma2(fyh, __hsub2(b1, b0), b0);
    __half2 s  = __hfma2(fzh, __hsub2(d, c), c);
    float2 sv = __half22float2(s);
    float sr = sv.x, si = sv.y;
    if (neg) si = -si;
    return make_float2(f.x*sr + f.y*si, f.y*sr - f.x*si);
}

// Main: XCD-swizzled; Nyquist tail + 4 chunks of Nk=16 (shift indexing,
// incremental coords); radix-4 x2 in LDS; folded x-irfft; wave argmax.
__global__ __launch_bounds__(256,5) void k_main(
    const u32* __restrict__ Yh, const float2* __restrict__ Fc,
    const float* __restrict__ rotm, const float* __restrict__ grid,
    float* __restrict__ resVal, int2* __restrict__ resShift)
{
    __shared__ float2 sP[DD*16];      // 16384 B
    __shared__ float2 sT[WIN*KX];     // 12480 B
    __shared__ float2 sTw[128];       // 1024 B
    __shared__ float  sM[9];
    __shared__ float  swv[4];
    __shared__ int    swi[4];

    int tid = threadIdx.x;
    int nb  = blockIdx.x;
    // bijective XCD swizzle: XCD (nb&7) processes orig-blocks [(nb&7)*125, ...)
    int blk = (nb & 7)*125 + (nb >> 3);
    int b  = blk / (NTT*NG);
    int rr = blk - b*NTT*NG;
    int t  = rr / NG;
    int g  = rr - t*NG;

    make_tw(sTw, tid);
    if (tid < 9){
        int i = tid/3, k = tid - 3*i;
        const float* R  = rotm + (b*NTT + t)*9;
        const float* Gm = grid + g*9;
        sM[tid] = R[i*3+0]*Gm[0*3+k] + R[i*3+1]*Gm[1*3+k] + R[i*3+2]*Gm[2*3+k];
    }
    __syncthreads();

    float M00=sM[0], M01=sM[1], M10=sM[3], M11=sM[4], M20=sM[6], M21=sM[7];
    const float2* FcB = Fc + b*DD*KX;

    // ---- Nyquist column k=64: direct 128-term y-IDFT ----
    if (tid < 128){
        int h = tid;
        float hf = (float)(h - 64);
        float xi = M01*hf + M00*64.f;
        float zi = M21*hf + M20*64.f + 64.f;
        float yi = M11*hf + M10*64.f + 64.f;
        sP[h] = slice_point(Yh, FcB[h*KX + 64], xi, zi, yi);
    }
    __syncthreads();
    if (tid < 96){
        int a = tid >> 2, p = tid & 3;
        int ry = (116 + a) & 127;
        int idx = (32*p*ry) & 127;
        float ar = 0.f, ai = 0.f;
        const float2* v = &sP[32*p];
        #pragma unroll 8
        for (int h2 = 0; h2 < 32; ++h2){
            float2 e = sTw[idx];
            float2 pv = v[h2];
            ar += pv.x*e.x - pv.y*e.y;
            ai += pv.x*e.y + pv.y*e.x;
            idx = (idx + ry) & 127;
        }
        sP[256 + tid] = make_float2(ar, ai);
    }
    __syncthreads();
    if (tid < 24){
        float2 p0 = sP[256 + tid*4 + 0];
        float2 p1 = sP[256 + tid*4 + 1];
        float2 p2 = sP[256 + tid*4 + 2];
        float2 p3 = sP[256 + tid*4 + 3];
        float sg = (tid & 1) ? -(1.f/128.f) : (1.f/128.f);
        sT[tid*KX + 64] = make_float2((p0.x+p1.x+p2.x+p3.x)*sg,
                                      (p0.y+p1.y+p2.y+p3.y)*sg);
    }
    __syncthreads();

    // ---- 4 chunks of 16 k-columns ----
    const int kk = tid & 15;
    const int h0 = tid >> 4;
    const float hf0 = (float)(h0 - 64);
    const float dxi = 16.f*M01, dzi = 16.f*M21, dyi = 16.f*M11;

    for (int cc = 0; cc < 4; ++cc){
        int w = cc*16 + kk;
        float wf = (float)w;
        float xi0 = M01*hf0 + M00*wf;
        float zi0 = M21*hf0 + M20*wf + 64.f;
        float yi0 = M11*hf0 + M10*wf + 64.f;
        int fidx = h0*KX + w;

        // Phase 1: 8 points per thread, incremental coords
        #pragma unroll 2
        for (int j = 0; j < 8; ++j){
            sP[tid + 256*j] = slice_point(Yh, FcB[fidx], xi0, zi0, yi0);
            xi0 += dxi; zi0 += dzi; yi0 += dyi; fidx += 16*KX;
        }
        __syncthreads();

        // Level 1 (inverse): identity indexing
        #pragma unroll
        for (int rep = 0; rep < 2; ++rep){
            int i = tid + 256*rep;
            float2 a  = sP[i];
            float2 bb = sP[i + 512];
            float2 c2 = sP[i + 1024];
            float2 d  = sP[i + 1536];
            float acx = a.x + c2.x, acy = a.y + c2.y;
            float amx = a.x - c2.x, amy = a.y - c2.y;
            float bdx = bb.x + d.x, bdy = bb.y + d.y;
            float bmx = bb.x - d.x, bmy = bb.y - d.y;
            sP[i       ] = make_float2(acx + bdx, acy + bdy);   // c=0
            sP[i + 512 ] = make_float2(amx - bmy, amy + bmx);   // c=1: + i(b-d)
            sP[i + 1024] = make_float2(acx - bdx, acy - bdy);   // c=2
            sP[i + 1536] = make_float2(amx + bmy, amy - bmx);   // c=3: - i(b-d)
        }
        __syncthreads();

        // Level 2 (inverse, in place)
        #pragma unroll
        for (int rep = 0; rep < 2; ++rep){
            int i = tid + 256*rep;
            int c = i >> 7, r7 = i & 127;
            int b0 = (c << 9) + r7;
            float2 u0 = sP[b0], u1 = sP[b0+128], u2 = sP[b0+256], u3 = sP[b0+384];
            float2 w1 = sTw[(8*c)&127], w2 = sTw[(16*c)&127], w3 = sTw[(24*c)&127];
            float2 t1 = cmul(u1,w1), t2 = cmul(u2,w2), t3 = cmul(u3,w3);
            float2 p  = make_float2(u0.x+t2.x, u0.y+t2.y);
            float2 qq = make_float2(u0.x-t2.x, u0.y-t2.y);
            float2 r  = make_float2(t1.x+t3.x, t1.y+t3.y);
            float2 s  = make_float2(t1.x-t3.x, t1.y-t3.y);
            sP[b0      ] = make_float2(p.x+r.x,  p.y+r.y);    // s=0
            sP[b0 + 128] = make_float2(qq.x-s.y, qq.y+s.x);   // s=1: q + i s
            sP[b0 + 256] = make_float2(p.x-r.x,  p.y-r.y);    // s=2
            sP[b0 + 384] = make_float2(qq.x+s.y, qq.y-s.x);   // s=3: q - i s
        }
        __syncthreads();

        // Phase 2: 8-term y-IDFT (384 items)
        for (int o = tid; o < 24*16; o += 256){
            int a = o >> 4, kx = o & 15;
            int ry = (116 + a) & 127;
            int c = ry & 3, s4 = (ry >> 2) & 3;
            const float2* v = &sP[(c << 9) + (s4 << 7) + kx];
            float ar0=0,ai0=0,ar1=0,ai1=0;
            int j2 = 0;
            #pragma unroll
            for (int n2 = 0; n2 < 8; n2 += 2){
                float2 v0 = v[n2*16], v1 = v[(n2+1)*16];
                float2 e0 = sTw[j2]; int jn = (j2 + ry)&127;
                float2 e1 = sTw[jn];
                ar0 += v0.x*e0.x - v0.y*e0.y;  ai0 += v0.x*e0.y + v0.y*e0.x;
                ar1 += v1.x*e1.x - v1.y*e1.y;  ai1 += v1.x*e1.y + v1.y*e1.x;
                j2 = (jn + ry)&127;
            }
            float sg = (a & 1) ? -(1.f/128.f) : (1.f/128.f);   // (-1)^ry / 128
            sT[a*KX + cc*16 + kx] = make_float2((ar0+ar1)*sg, (ai0+ai1)*sg);
        }
        __syncthreads();
    }

    // Phase 3a: Hermitian fold into sP (free): Ae (even rx) / Ao (odd rx)
    float2* sPf = sP;
    for (int o = tid; o < WIN*31; o += 256){
        int a = o / 31, km1 = o - a*31;
        int k = km1 + 1;
        const float2* Trow = &sT[a*KX];
        float2 T1 = Trow[k], T2 = Trow[64-k];
        sPf[a*31 + km1]       = make_float2(T1.x + T2.x, T1.y - T2.y);
        sPf[744 + a*31 + km1] = make_float2(T1.x - T2.x, T1.y + T2.y);
    }
    __syncthreads();

    // Phase 3b: 31-term folded x-irfft on the 24x24 window
    float* sC = reinterpret_cast<float*>(sP + 1488);
    for (int o = tid; o < WIN*WIN; o += 256){
        int a = o / WIN, bx = o - a*WIN;
        int rx = (116 + bx) & 127;
        const float2* Trow = &sT[a*KX];
        float2 T32 = Trow[32];
        float base = Trow[0].x + ((bx & 1) ? -Trow[64].x : Trow[64].x);
        int r4 = rx & 3;
        base += (r4==0) ?  2.f*T32.x : (r4==1) ? -2.f*T32.y
              : (r4==2) ? -2.f*T32.x :  2.f*T32.y;
        const float2* A = sPf + ((bx & 1) ? 744 : 0) + a*31 - 1;  // A[k], k=1..31
        float acc0 = 0.f, acc1 = 0.f;
        int j1 = rx, j2 = (2*rx)&127;
        int st = (2*rx)&127;
        for (int k = 1; k < 31; k += 2){
            float2 e1 = sTw[j1]; float2 A1v = A[k];
            float2 e2 = sTw[j2]; float2 A2v = A[k+1];
            acc0 += A1v.x*e1.x - A1v.y*e1.y;
            acc1 += A2v.x*e2.x - A2v.y*e2.y;
            j1=(j1+st)&127; j2=(j2+st)&127;
        }
        {
            float2 e = sTw[(31*rx)&127]; float2 Av = A[31];
            acc0 += Av.x*e.x - Av.y*e.y;
        }
        sC[o] = (base + 2.f*(acc0+acc1))*(1.f/128.f);
    }
    __syncthreads();

    // Phase 4: argmax, row-major first occurrence — wave shfl_xor reduce
    float best = -FLT_MAX; int bidx = 0x7fffffff;
    for (int i = tid; i < WIN*WIN; i += 256){
        float v = sC[i];
        if (v > best){ best = v; bidx = i; }
    }
    #pragma unroll
    for (int s = 32; s > 0; s >>= 1){
        float ov = __shfl_xor(best, s, 64);
        int   oi = __shfl_xor(bidx, s, 64);
        if (ov > best || (ov == best && oi < bidx)){ best = ov; bidx = oi; }
    }
    if ((tid & 63) == 0){ swv[tid>>6] = best; swi[tid>>6] = bidx; }
    __syncthreads();
    if (tid == 0){
        float bv = swv[0]; int bi = swi[0];
        #pragma unroll
        for (int w2 = 1; w2 < 4; ++w2){
            if (swv[w2] > bv || (swv[w2] == bv && swi[w2] < bi)){ bv = swv[w2]; bi = swi[w2]; }
        }
        int a = bi / WIN, bx = bi - a*WIN;
        resVal[blk] = bv;
        resShift[blk] = make_int2(H0 + bx, H0 + a);
    }
}

// Final: per-batch top-2 (stable ties), mean/std(ddof=1), erf — parallel.
__global__ __launch_bounds__(256) void k_final(const float* __restrict__ resVal,
                        const int2* __restrict__ resShift,
                        const float* __restrict__ grid, float* __restrict__ out)
{
    __shared__ float sv[256];
    __shared__ int   si[256];
    __shared__ float sr[256];
    __shared__ float sMean;
    const int N = NTT*NG;   // 250
    int b = blockIdx.x, tid = threadIdx.x;
    const float* v = resVal + b*N;
    float myv = (tid < N) ? v[tid] : -FLT_MAX;

    sv[tid] = myv; si[tid] = (tid < N) ? tid : 0x7fffffff;
    __syncthreads();
    for (int s = 128; s > 0; s >>= 1){
        if (tid < s){
            float v2 = sv[tid+s]; int i2 = si[tid+s];
            if (v2 > sv[tid] || (v2 == sv[tid] && i2 < si[tid])){ sv[tid]=v2; si[tid]=i2; }
        }
        __syncthreads();
    }
    float v0 = sv[0]; int i0 = si[0];
    __syncthreads();

    bool act = (tid < N) && (tid != i0);
    sv[tid] = act ? myv : -FLT_MAX; si[tid] = act ? tid : 0x7fffffff;
    __syncthreads();
    for (int s = 128; s > 0; s >>= 1){
        if (tid < s){
            float v2 = sv[tid+s]; int i2 = si[tid+s];
            if (v2 > sv[tid] || (v2 == sv[tid] && i2 < si[tid])){ sv[tid]=v2; si[tid]=i2; }
        }
        __syncthreads();
    }
    float v1 = sv[0]; int i1 = si[0];
    __syncthreads();

    sr[tid] = (tid < N) ? myv : 0.f;
    __syncthreads();
    for (int s = 128; s > 0; s >>= 1){
        if (tid < s) sr[tid] += sr[tid+s];
        __syncthreads();
    }
    if (tid == 0) sMean = sr[0] / (float)N;
    __syncthreads();
    float mean = sMean;

    float d = (tid < N) ? (myv - mean) : 0.f;
    sr[tid] = d*d;
    __syncthreads();
    for (int s = 128; s > 0; s >>= 1){
        if (tid < s) sr[tid] += sr[tid+s];
        __syncthreads();
    }

    if (tid == 0){
        float stdv = sqrtf(sr[0] / (float)(N - 1));
        float vals[2] = {v0, v1};
        int   idxs[2] = {i0, i1};
        for (int k = 0; k < 2; ++k){
            out[b*2 + k] = vals[k];
            int gi = idxs[k] % NG;
            for (int j = 0; j < 9; ++j) out[8 + (b*2+k)*9 + j] = grid[gi*9 + j];
            int2 sh = resShift[b*N + idxs[k]];
            out[80 + (b*2+k)*2 + 0] = -((float)sh.x - 64.f)*1.5f;
            out[80 + (b*2+k)*2 + 1] = -((float)sh.y - 64.f)*1.5f;
            out[96 + b*2 + k] = 0.5f*(1.f + erff((vals[k] - mean)/(stdv*1.41421356237309515f)));
        }
    }
}

extern "C" void kernel_launch(void* const* d_in, const int* in_sizes, int n_in,
                              void* d_out, int out_size, void* d_ws, size_t ws_size,
                              hipStream_t stream)
{
    const float* vol  = (const float*)d_in[0];
    const float* imgs = (const float*)d_in[1];
    const float* ctf  = (const float*)d_in[2];
    const float* rotm = (const float*)d_in[3];
    const float* grid = (const float*)d_in[4];
    float* out = (float*)d_out;

    const size_t YH_BYTES  = (size_t)QN*8;                      // 9,406,848
    const size_t A1_BYTES  = (size_t)DD*DD*KX*sizeof(float2);   // 8,519,680
    const size_t B1_BYTES  = (size_t)NB*DD*KX*sizeof(float2);   //   266,240

    char* ws = (char*)d_ws;
    // Yh is NOT aliased (zeroed concurrently with stageA's FFT blocks)
    u32*    Yh = (u32*)(ws);
    size_t off = YH_BYTES;
    float2* A1 = (float2*)(ws + off); off += A1_BYTES;
    float2* B1 = (float2*)(ws + off); off += B1_BYTES;
    float2* A2 = (float2*)(ws + off); off += A1_BYTES;
    float2* Fc = (float2*)(ws + off); off += B1_BYTES;
    float* resVal = (float*)(ws + off); off += (size_t)NBTG*sizeof(float);
    int2* resShift = (int2*)(ws + off); off += (size_t)NBTG*sizeof(int2);

    const int n4 = (int)(YH_BYTES / 16);   // uint4 count
    k_stageA<<<898, 256, 0, stream>>>(vol, imgs, A1, B1, (uint4*)Yh, n4);
    k_stageB<<<642, 256, 0, stream>>>(A1, ctf, B1, A2, Fc);
    k_volD  <<<512, 256, 0, stream>>>(A2, Yh);
    k_main  <<<NBTG,256, 0, stream>>>(Yh, Fc, rotm, grid, resVal, resShift);
    k_final <<<NB,  256, 0, stream>>>(resVal, resShift, grid, out);
}